// Round 1
// baseline (567.359 us; speedup 1.0000x reference)
//
#include <hip/hip_runtime.h>
#include <stdint.h>

// out = x @ dequant(W)^T + bias
// x: [M,K] fp32 (M = B*S = 8192), W_q: [N,K] int32 codes in [0,4),
// scale/zp: [N, K/G] fp32 (G=64), bias: [N] fp32, out: [M,N] fp32.
//
// Plan: (1) cvt x -> bf16 in ws, (2) dequant W -> bf16 (N,K layout) in ws,
// (3) m97-style 128x128-tile bf16 MFMA GEMM (gemm_bt) with fused bias.

typedef __attribute__((ext_vector_type(4))) float  f32x4;
typedef __attribute__((ext_vector_type(4))) int    i32x4;
typedef __attribute__((ext_vector_type(8))) __bf16 bf16x8;
typedef __attribute__((ext_vector_type(8))) unsigned short u16x8;

__device__ __forceinline__ unsigned short f2bf(float f) {
  unsigned u = __builtin_bit_cast(unsigned, f);
  u += 0x7fffu + ((u >> 16) & 1u);   // round-to-nearest-even
  return (unsigned short)(u >> 16);
}

__device__ __forceinline__ void async16(const void* g, void* l) {
  __builtin_amdgcn_global_load_lds(
      (const __attribute__((address_space(1))) unsigned int*)g,
      (__attribute__((address_space(3))) unsigned int*)l, 16, 0, 0);
}

// ---------------- prepass 1: x fp32 -> bf16 ----------------
__global__ __launch_bounds__(256) void cvt_x_kernel(
    const float* __restrict__ x, unsigned short* __restrict__ xb, int total8) {
  int i = blockIdx.x * 256 + threadIdx.x;
  if (i >= total8) return;
  const f32x4* p = (const f32x4*)x + (size_t)i * 2;
  f32x4 a = p[0], b = p[1];
  u16x8 o;
  o[0] = f2bf(a[0]); o[1] = f2bf(a[1]); o[2] = f2bf(a[2]); o[3] = f2bf(a[3]);
  o[4] = f2bf(b[0]); o[5] = f2bf(b[1]); o[6] = f2bf(b[2]); o[7] = f2bf(b[3]);
  *(u16x8*)(xb + (size_t)i * 8) = o;
}

// ---------------- prepass 2: dequant W -> bf16 (N,K) ----------------
__global__ __launch_bounds__(256) void dequant_w_kernel(
    const int* __restrict__ q, const float* __restrict__ scale,
    const float* __restrict__ zp, unsigned short* __restrict__ wb,
    int N, int K, int G) {
  int kchunks = K / 8;
  int i = blockIdx.x * 256 + threadIdx.x;
  if (i >= N * kchunks) return;
  int n = i / kchunks, kc = i % kchunks;
  int k0 = kc * 8;
  int ng = K / G;
  int g = k0 / G;
  float s = scale[(size_t)n * ng + g];
  float b = -zp[(size_t)n * ng + g] * s;   // w = q*s + b
  const i32x4* qp = (const i32x4*)(q + (size_t)n * K + k0);
  i32x4 q0 = qp[0], q1 = qp[1];
  u16x8 o;
  o[0] = f2bf((float)q0[0] * s + b); o[1] = f2bf((float)q0[1] * s + b);
  o[2] = f2bf((float)q0[2] * s + b); o[3] = f2bf((float)q0[3] * s + b);
  o[4] = f2bf((float)q1[0] * s + b); o[5] = f2bf((float)q1[1] * s + b);
  o[6] = f2bf((float)q1[2] * s + b); o[7] = f2bf((float)q1[3] * s + b);
  *(u16x8*)(wb + (size_t)i * 8) = o;
}

// ---------------- main GEMM: C[M,N] = A[M,K] * B[N,K]^T + bias ----------------
#define BM 128
#define BN 128
#define BK 32

__global__ __launch_bounds__(256, 2) void gemm_bt_kernel(
    const unsigned short* __restrict__ A,   // M x K bf16
    const unsigned short* __restrict__ B,   // N x K bf16 (already transposed layout)
    const float* __restrict__ bias,
    float* __restrict__ C, int M, int N, int K) {
  __shared__ unsigned short As[BM * BK];    // 8 KB
  __shared__ unsigned short Bs[BN * BK];    // 8 KB

  const int tid  = threadIdx.x;
  const int lane = tid & 63;
  const int wave = tid >> 6;                // 4 waves, 2x2 over the 128x128 tile
  const int wm = wave >> 1, wn = wave & 1;
  const int q = lane >> 4, r = lane & 15;   // MFMA quad / row-in-16
  const int m0 = blockIdx.y * BM;
  const int n0 = blockIdx.x * BN;

  // staging: thread tid stages 16B chunk (row = tid/4 (+64), chunk = tid&3).
  // LDS offset (row*32 + chunk*8) halfwords == tid*8 -> wave-uniform base + lane*16B. 
  const int srow = tid >> 2, schunk = tid & 3;
  const unsigned short* aG0 = A + (size_t)(m0 + srow) * K      + schunk * 8;
  const unsigned short* aG1 = A + (size_t)(m0 + 64 + srow) * K + schunk * 8;
  const unsigned short* bG0 = B + (size_t)(n0 + srow) * K      + schunk * 8;
  const unsigned short* bG1 = B + (size_t)(n0 + 64 + srow) * K + schunk * 8;
  unsigned short* aL0 = &As[tid * 8];
  unsigned short* aL1 = &As[2048 + tid * 8];
  unsigned short* bL0 = &Bs[tid * 8];
  unsigned short* bL1 = &Bs[2048 + tid * 8];

  f32x4 acc[4][4] = {};

#pragma unroll 1
  for (int kk = 0; kk < K; kk += BK) {
    async16(aG0 + kk, aL0);
    async16(aG1 + kk, aL1);
    async16(bG0 + kk, bL0);
    async16(bG1 + kk, bL1);
    __syncthreads();   // drains vmcnt (global_load_lds) + cross-wave

    bf16x8 af[4], bf[4];
#pragma unroll
    for (int i = 0; i < 4; ++i) {
      af[i] = *(const bf16x8*)&As[(wm * 64 + i * 16 + r) * BK + q * 8];
      bf[i] = *(const bf16x8*)&Bs[(wn * 64 + i * 16 + r) * BK + q * 8];
    }
#pragma unroll
    for (int i = 0; i < 4; ++i)
#pragma unroll
      for (int j = 0; j < 4; ++j)
        acc[i][j] = __builtin_amdgcn_mfma_f32_16x16x32_bf16(af[i], bf[j], acc[i][j], 0, 0, 0);
    __syncthreads();   // all waves done reading LDS before next overwrite
  }

  // epilogue: C/D layout col = lane&15, row = quad*4 + reg
  float bv[4];
#pragma unroll
  for (int j = 0; j < 4; ++j) bv[j] = bias[n0 + wn * 64 + j * 16 + r];
#pragma unroll
  for (int i = 0; i < 4; ++i) {
    int mbase = m0 + wm * 64 + i * 16 + q * 4;
#pragma unroll
    for (int e = 0; e < 4; ++e) {
      float* crow = C + (size_t)(mbase + e) * N + n0 + wn * 64 + r;
#pragma unroll
      for (int j = 0; j < 4; ++j)
        crow[j * 16] = acc[i][j][e] + bv[j];
    }
  }
}

// ---------------- correctness fallback (only if ws too small) ----------------
__global__ __launch_bounds__(256) void naive_kernel(
    const float* __restrict__ x, const int* __restrict__ wq,
    const float* __restrict__ scale, const float* __restrict__ zp,
    const float* __restrict__ bias, float* __restrict__ out,
    int M, int N, int K, int G) {
  int idx = blockIdx.x * 256 + threadIdx.x;
  if (idx >= M * N) return;
  int m = idx / N, n = idx % N;
  const float* xr = x + (size_t)m * K;
  const int* wr = wq + (size_t)n * K;
  int ng = K / G;
  float acc = 0.f;
  for (int g = 0; g < ng; ++g) {
    float s = scale[(size_t)n * ng + g];
    float b = -zp[(size_t)n * ng + g] * s;
    for (int k = 0; k < G; ++k)
      acc += xr[g * G + k] * ((float)wr[g * G + k] * s + b);
  }
  out[idx] = acc + bias[n];
}

extern "C" void kernel_launch(void* const* d_in, const int* in_sizes, int n_in,
                              void* d_out, int out_size, void* d_ws, size_t ws_size,
                              hipStream_t stream) {
  const float* x     = (const float*)d_in[0];
  const int*   wq    = (const int*)d_in[1];
  const float* scale = (const float*)d_in[2];
  const float* zp    = (const float*)d_in[3];
  const float* bias  = (const float*)d_in[4];
  float* out = (float*)d_out;

  const int N  = in_sizes[4];
  const int K  = in_sizes[1] / N;
  const int ng = in_sizes[2] / N;
  const int G  = K / ng;
  const int M  = in_sizes[0] / K;

  size_t xb_bytes = (size_t)M * K * 2;
  size_t wb_bytes = (size_t)N * K * 2;
  if (ws_size < xb_bytes + wb_bytes) {
    int total = M * N;
    naive_kernel<<<dim3((total + 255) / 256), dim3(256), 0, stream>>>(
        x, wq, scale, zp, bias, out, M, N, K, G);
    return;
  }

  unsigned short* xb = (unsigned short*)d_ws;
  unsigned short* wb = (unsigned short*)((char*)d_ws + xb_bytes);

  int xt = M * K / 8;
  cvt_x_kernel<<<dim3((xt + 255) / 256), dim3(256), 0, stream>>>(x, xb, xt);
  int wt = N * K / 8;
  dequant_w_kernel<<<dim3((wt + 255) / 256), dim3(256), 0, stream>>>(wq, scale, zp, wb, N, K, G);

  dim3 grid(N / BN, M / BM);
  gemm_bt_kernel<<<grid, dim3(256), 0, stream>>>(xb, wb, bias, out, M, N, K);
}

// Round 2
// 561.423 us; speedup vs baseline: 1.0106x; 1.0106x over previous
//
#include <hip/hip_runtime.h>
#include <stdint.h>

// out = x @ dequant(W)^T + bias
// x: [M,K] fp32 (M=B*S=8192), W_q: [N,K] int32 codes in [0,4),
// scale/zp: [N,K/G] fp32 (G=64), bias: [N] fp32, out: [M,N] fp32.
//
// R2: (1) single fused prepass (x->bf16, dequant W->bf16) with perfect 16B
// coalescing; (2) GEMM LDS chunk swizzle (c ^= (row>>1)&3) to kill the 8-way
// ds_read_b128 bank conflicts (3.35e7 in R1).

typedef __attribute__((ext_vector_type(4))) float  f32x4;
typedef __attribute__((ext_vector_type(4))) int    i32x4;
typedef __attribute__((ext_vector_type(8))) __bf16 bf16x8;
typedef __attribute__((ext_vector_type(4))) unsigned short u16x4;

__device__ __forceinline__ unsigned short f2bf(float f) {
  unsigned u = __builtin_bit_cast(unsigned, f);
  u += 0x7fffu + ((u >> 16) & 1u);   // round-to-nearest-even
  return (unsigned short)(u >> 16);
}

__device__ __forceinline__ void async16(const void* g, void* l) {
  __builtin_amdgcn_global_load_lds(
      (const __attribute__((address_space(1))) unsigned int*)g,
      (__attribute__((address_space(3))) unsigned int*)l, 16, 0, 0);
}

// ---------------- fused prepass: x->bf16 and dequant W->bf16 ----------------
// x-part: thread i handles 4 floats (16B load, 8B store).
// w-part: thread i handles 4 codes (16B load, 8B store).
__global__ __launch_bounds__(256) void prep_kernel(
    const float* __restrict__ x, unsigned short* __restrict__ xb, int xchunks,
    const int* __restrict__ wq, const float* __restrict__ scale,
    const float* __restrict__ zp, unsigned short* __restrict__ wb,
    int wchunks, int K, int G) {
  int xblocks = (xchunks + 255) >> 8;
  if ((int)blockIdx.x < xblocks) {
    int i = blockIdx.x * 256 + threadIdx.x;
    if (i >= xchunks) return;
    f32x4 a = ((const f32x4*)x)[i];
    u16x4 o;
    o[0] = f2bf(a[0]); o[1] = f2bf(a[1]); o[2] = f2bf(a[2]); o[3] = f2bf(a[3]);
    *(u16x4*)(xb + (size_t)i * 4) = o;
  } else {
    int i = (blockIdx.x - xblocks) * 256 + threadIdx.x;
    if (i >= wchunks) return;
    int k4 = i * 4;
    int n = k4 / K, kk = k4 % K;
    int ng = K / G;
    int g = kk / G;
    float s = scale[(size_t)n * ng + g];
    float b = -zp[(size_t)n * ng + g] * s;   // w = q*s + b
    i32x4 qv = ((const i32x4*)wq)[i];
    u16x4 o;
    o[0] = f2bf((float)qv[0] * s + b); o[1] = f2bf((float)qv[1] * s + b);
    o[2] = f2bf((float)qv[2] * s + b); o[3] = f2bf((float)qv[3] * s + b);
    *(u16x4*)(wb + (size_t)i * 4) = o;
  }
}

// ---------------- main GEMM: C[M,N] = A[M,K] * B[N,K]^T + bias ----------------
#define BM 128
#define BN 128
#define BK 32

__global__ __launch_bounds__(256, 2) void gemm_bt_kernel(
    const unsigned short* __restrict__ A,   // M x K bf16
    const unsigned short* __restrict__ B,   // N x K bf16
    const float* __restrict__ bias,
    float* __restrict__ C, int M, int N, int K) {
  __shared__ unsigned short As[BM * BK];    // 8 KB
  __shared__ unsigned short Bs[BN * BK];    // 8 KB

  const int tid  = threadIdx.x;
  const int lane = tid & 63;
  const int wave = tid >> 6;                // 4 waves, 2x2 over the 128x128 tile
  const int wm = wave >> 1, wn = wave & 1;
  const int q = lane >> 4, r = lane & 15;   // MFMA K-slice / row-in-16
  const int m0 = blockIdx.y * BM;
  const int n0 = blockIdx.x * BN;

  // Staging: thread tid owns LDS slot (row=tid>>2, slot=tid&3) — forced by
  // global_load_lds (wave base + lane*16B). Swizzle: slot s of row holds
  // GLOBAL chunk s ^ ((row>>1)&3), so each lane fetches that chunk.
  const int srow = tid >> 2, schunk = tid & 3;
  const int gchunk = schunk ^ ((srow >> 1) & 3);
  const unsigned short* aG0 = A + (size_t)(m0 + srow) * K      + gchunk * 8;
  const unsigned short* aG1 = A + (size_t)(m0 + 64 + srow) * K + gchunk * 8;
  const unsigned short* bG0 = B + (size_t)(n0 + srow) * K      + gchunk * 8;
  const unsigned short* bG1 = B + (size_t)(n0 + 64 + srow) * K + gchunk * 8;
  // (row 64+srow has the same swizzle key: ((64+srow)>>1)&3 == (srow>>1)&3)
  unsigned short* aL0 = &As[tid * 8];
  unsigned short* aL1 = &As[2048 + tid * 8];
  unsigned short* bL0 = &Bs[tid * 8];
  unsigned short* bL1 = &Bs[2048 + tid * 8];

  // Read-side swizzled slot for chunk q: q ^ ((row>>1)&3); row = base16 + r
  // with base16 % 16 == 0, so key = (r>>1)&3 — constant per lane.
  const int qc = (q ^ ((r >> 1) & 3)) * 8;

  f32x4 acc[4][4] = {};

#pragma unroll 1
  for (int kk = 0; kk < K; kk += BK) {
    async16(aG0 + kk, aL0);
    async16(aG1 + kk, aL1);
    async16(bG0 + kk, bL0);
    async16(bG1 + kk, bL1);
    __syncthreads();   // drains vmcnt (global_load_lds) + cross-wave

    bf16x8 af[4], bf[4];
#pragma unroll
    for (int i = 0; i < 4; ++i) {
      af[i] = *(const bf16x8*)&As[(wm * 64 + i * 16 + r) * BK + qc];
      bf[i] = *(const bf16x8*)&Bs[(wn * 64 + i * 16 + r) * BK + qc];
    }
#pragma unroll
    for (int i = 0; i < 4; ++i)
#pragma unroll
      for (int j = 0; j < 4; ++j)
        acc[i][j] = __builtin_amdgcn_mfma_f32_16x16x32_bf16(af[i], bf[j], acc[i][j], 0, 0, 0);
    __syncthreads();   // all waves done reading LDS before next overwrite
  }

  // epilogue: C/D layout col = lane&15, row = quad*4 + reg
  float bv[4];
#pragma unroll
  for (int j = 0; j < 4; ++j) bv[j] = bias[n0 + wn * 64 + j * 16 + r];
#pragma unroll
  for (int i = 0; i < 4; ++i) {
    int mbase = m0 + wm * 64 + i * 16 + q * 4;
#pragma unroll
    for (int e = 0; e < 4; ++e) {
      float* crow = C + (size_t)(mbase + e) * N + n0 + wn * 64 + r;
#pragma unroll
      for (int j = 0; j < 4; ++j)
        crow[j * 16] = acc[i][j][e] + bv[j];
    }
  }
}

// ---------------- correctness fallback (only if ws too small) ----------------
__global__ __launch_bounds__(256) void naive_kernel(
    const float* __restrict__ x, const int* __restrict__ wq,
    const float* __restrict__ scale, const float* __restrict__ zp,
    const float* __restrict__ bias, float* __restrict__ out,
    int M, int N, int K, int G) {
  int idx = blockIdx.x * 256 + threadIdx.x;
  if (idx >= M * N) return;
  int m = idx / N, n = idx % N;
  const float* xr = x + (size_t)m * K;
  const int* wr = wq + (size_t)n * K;
  int ng = K / G;
  float acc = 0.f;
  for (int g = 0; g < ng; ++g) {
    float s = scale[(size_t)n * ng + g];
    float b = -zp[(size_t)n * ng + g] * s;
    for (int k = 0; k < G; ++k)
      acc += xr[g * G + k] * ((float)wr[g * G + k] * s + b);
  }
  out[idx] = acc + bias[n];
}

extern "C" void kernel_launch(void* const* d_in, const int* in_sizes, int n_in,
                              void* d_out, int out_size, void* d_ws, size_t ws_size,
                              hipStream_t stream) {
  const float* x     = (const float*)d_in[0];
  const int*   wq    = (const int*)d_in[1];
  const float* scale = (const float*)d_in[2];
  const float* zp    = (const float*)d_in[3];
  const float* bias  = (const float*)d_in[4];
  float* out = (float*)d_out;

  const int N  = in_sizes[4];
  const int K  = in_sizes[1] / N;
  const int ng = in_sizes[2] / N;
  const int G  = K / ng;
  const int M  = in_sizes[0] / K;

  size_t xb_bytes = (size_t)M * K * 2;
  size_t wb_bytes = (size_t)N * K * 2;
  if (ws_size < xb_bytes + wb_bytes) {
    int total = M * N;
    naive_kernel<<<dim3((total + 255) / 256), dim3(256), 0, stream>>>(
        x, wq, scale, zp, bias, out, M, N, K, G);
    return;
  }

  unsigned short* xb = (unsigned short*)d_ws;
  unsigned short* wb = (unsigned short*)((char*)d_ws + xb_bytes);

  int xchunks = M * K / 4;
  int wchunks = N * K / 4;
  int xblocks = (xchunks + 255) / 256;
  int wblocks = (wchunks + 255) / 256;
  prep_kernel<<<dim3(xblocks + wblocks), dim3(256), 0, stream>>>(
      x, xb, xchunks, wq, scale, zp, wb, wchunks, K, G);

  dim3 grid(N / BN, M / BM);
  gemm_bt_kernel<<<grid, dim3(256), 0, stream>>>(xb, wb, bias, out, M, N, K);
}